// Round 1
// baseline (301.914 us; speedup 1.0000x reference)
//
#include <hip/hip_runtime.h>
#include <hip/hip_fp16.h>

#define N_ 16
#define C_ 128
#define S_ 16384
#define K_ 64

// ---------------------------------------------------------------------------
// K2: per-thread position. Load x[:,s] into regs, L2-norm, logits (w via
// uniform/scalar loads), softmax over K, write soft' = soft * (1/||x||) as
// fp16, accumulate a_sum = sum_s soft via block reduce + atomics.
// ---------------------------------------------------------------------------
__global__ __launch_bounds__(128) void softassign_kernel(
    const float* __restrict__ x, const float* __restrict__ fc_w,
    const float* __restrict__ fc_b, __half* __restrict__ softp,
    float* __restrict__ a_sum)
{
    __shared__ float st[128][66];   // [thread][k], stride 66 -> 2-way (free)
    const int tid = threadIdx.x;
    const int p = blockIdx.x * 128 + tid;
    const int n = p >> 14;          // p / S_
    const int s = p & (S_ - 1);

    const float* xp = x + (size_t)n * C_ * S_ + s;
    float xv[C_];
    float s0 = 0.f, s1 = 0.f, s2 = 0.f, s3 = 0.f;
#pragma unroll
    for (int c = 0; c < C_; c += 4) {
        xv[c+0] = xp[(size_t)(c+0) * S_];
        xv[c+1] = xp[(size_t)(c+1) * S_];
        xv[c+2] = xp[(size_t)(c+2) * S_];
        xv[c+3] = xp[(size_t)(c+3) * S_];
        s0 += xv[c+0]*xv[c+0]; s1 += xv[c+1]*xv[c+1];
        s2 += xv[c+2]*xv[c+2]; s3 += xv[c+3]*xv[c+3];
    }
    const float rn = 1.0f / fmaxf(sqrtf((s0+s1)+(s2+s3)), 1e-12f);

    // pass 1: logits -> LDS, track max
    float m = -1e30f;
#pragma unroll 1
    for (int k = 0; k < K_; ++k) {
        const float* wr = fc_w + k * C_;   // uniform address -> s_load
        float d0 = 0.f, d1 = 0.f, d2 = 0.f, d3 = 0.f;
#pragma unroll
        for (int c = 0; c < C_; c += 4) {
            d0 += xv[c+0] * wr[c+0];
            d1 += xv[c+1] * wr[c+1];
            d2 += xv[c+2] * wr[c+2];
            d3 += xv[c+3] * wr[c+3];
        }
        float l = ((d0+d1)+(d2+d3)) * rn + fc_b[k];
        st[tid][k] = l;
        m = fmaxf(m, l);
    }
    // pass 2: exp, sum
    float sum = 0.f;
#pragma unroll 1
    for (int k = 0; k < K_; ++k) {
        float e = expf(st[tid][k] - m);
        st[tid][k] = e;
        sum += e;
    }
    const float binv = 1.0f / sum;   // soft  = e * binv
    const float ainv = binv * rn;    // soft' = e * binv * rn
    // pass 3: write soft' (fp16, coalesced over s), keep soft in LDS for a_sum
    __half* op = softp + (size_t)n * K_ * S_ + s;
#pragma unroll 1
    for (int k = 0; k < K_; ++k) {
        float e = st[tid][k];
        op[(size_t)k * S_] = __float2half(e * ainv);
        st[tid][k] = e * binv;
    }
    __syncthreads();
    // a_sum block reduce: thread k sums its column over 128 rows
    if (tid < K_) {
        float t = 0.f;
#pragma unroll 1
        for (int r = 0; r < 128; ++r) t += st[r][tid];
        atomicAdd(a_sum + n * K_ + tid, t);
    }
}

// ---------------------------------------------------------------------------
// K3: vlad[n,k,c] += sum_s soft'[k,s] * x_raw[c,s].  Block = 128 threads,
// thread owns 8k x 8c (c strided by 16 => conflict-free & coalesced atomics).
// float4 LDS reads over s with kt-rotated sl to avoid bank degeneracy.
// ---------------------------------------------------------------------------
__global__ __launch_bounds__(128) void vlad_kernel(
    const float* __restrict__ x, const __half* __restrict__ softp,
    float* __restrict__ vlad_acc)
{
    __shared__ __align__(16) float st[K_][36];    // 9.2 KB
    __shared__ __align__(16) float xt[C_][36];    // 18.4 KB
    const int tid = threadIdx.x;
    const int NCH = 32;                   // s-chunks per n
    const int n = blockIdx.x / NCH;
    const int chunk = blockIdx.x % NCH;
    const int SCH = S_ / NCH;             // 512
    const int sbase = chunk * SCH;
    const int kt = tid >> 4;              // 0..7 (8 k each)
    const int ct = tid & 15;              // 0..15 (8 c each, stride 16)

    float acc[8][8];
#pragma unroll
    for (int i = 0; i < 8; ++i)
#pragma unroll
        for (int j = 0; j < 8; ++j) acc[i][j] = 0.f;

    const float* xbase = x + (size_t)n * C_ * S_;
    const __half* sbase_p = softp + (size_t)n * K_ * S_;

#pragma unroll 1
    for (int sub = 0; sub < SCH / 32; ++sub) {
        const int s0 = sbase + sub * 32;
        // stage x tile [128c][32s] (pad 36)
#pragma unroll
        for (int j = 0; j < 32; ++j) {
            int idx = j * 128 + tid;
            int c = idx >> 5, sl = idx & 31;
            xt[c][sl] = xbase[(size_t)c * S_ + s0 + sl];
        }
        // stage soft' tile [64k][32s] (pad 36), fp16 -> fp32
#pragma unroll
        for (int j = 0; j < 16; ++j) {
            int idx = j * 128 + tid;
            int k = idx >> 5, sl = idx & 31;
            st[k][sl] = __half2float(sbase_p[(size_t)k * S_ + s0 + sl]);
        }
        __syncthreads();

#pragma unroll
        for (int r = 0; r < 8; ++r) {
            const int sl4 = ((r + kt) & 7) * 4;   // rotation: bank spread
            float4 sv[8], xv[8];
#pragma unroll
            for (int i = 0; i < 8; ++i)
                sv[i] = *(const float4*)&st[kt * 8 + i][sl4];
#pragma unroll
            for (int j = 0; j < 8; ++j)
                xv[j] = *(const float4*)&xt[ct + 16 * j][sl4];
#pragma unroll
            for (int i = 0; i < 8; ++i)
#pragma unroll
                for (int j = 0; j < 8; ++j) {
                    acc[i][j] += sv[i].x * xv[j].x;
                    acc[i][j] += sv[i].y * xv[j].y;
                    acc[i][j] += sv[i].z * xv[j].z;
                    acc[i][j] += sv[i].w * xv[j].w;
                }
        }
        __syncthreads();
    }

    float* vp = vlad_acc + (size_t)n * K_ * C_;
#pragma unroll
    for (int i = 0; i < 8; ++i)
#pragma unroll
        for (int j = 0; j < 8; ++j)
            atomicAdd(vp + (kt * 8 + i) * C_ + ct + 16 * j, acc[i][j]);
}

// ---------------------------------------------------------------------------
// K4: vlad -= a_sum*centroids; intra-norm over C; global norm over K*C.
// Block per n; thread t: k = t>>2, owns c = (t&3) + 4j.
// ---------------------------------------------------------------------------
__global__ __launch_bounds__(256) void finalize_kernel(
    const float* __restrict__ vlad_acc, const float* __restrict__ a_sum,
    const float* __restrict__ centroids, float* __restrict__ out)
{
    __shared__ float red[4];
    const int n = blockIdx.x;
    const int t = threadIdx.x;
    const int k = t >> 2, q = t & 3;
    const float av = a_sum[n * K_ + k];
    const float* vp = vlad_acc + ((size_t)n * K_ + k) * C_;
    const float* cp = centroids + k * C_;

    float v[32];
    float ssq = 0.f;
#pragma unroll
    for (int j = 0; j < 32; ++j) {
        int c = q + 4 * j;
        float val = vp[c] - av * cp[c];
        v[j] = val;
        ssq += val * val;
    }
    // 4 lanes (same k) hold partials: lanes t, t^1, t^2 are contiguous
    ssq += __shfl_xor(ssq, 1);
    ssq += __shfl_xor(ssq, 2);
    const float inv1 = 1.0f / fmaxf(sqrtf(ssq), 1e-12f);

    // global sum of vn^2 : contribute once per k
    float gp = (q == 0) ? ssq * inv1 * inv1 : 0.f;
#pragma unroll
    for (int off = 1; off < 64; off <<= 1) gp += __shfl_xor(gp, off);
    if ((t & 63) == 0) red[t >> 6] = gp;
    __syncthreads();
    const float G = red[0] + red[1] + red[2] + red[3];
    const float ginv = 1.0f / fmaxf(sqrtf(G), 1e-12f);

    float* op = out + (size_t)n * (K_ * C_) + k * C_;
#pragma unroll
    for (int j = 0; j < 32; ++j) op[q + 4 * j] = v[j] * inv1 * ginv;
}

extern "C" void kernel_launch(void* const* d_in, const int* in_sizes, int n_in,
                              void* d_out, int out_size, void* d_ws, size_t ws_size,
                              hipStream_t stream) {
    const float* x     = (const float*)d_in[0];
    const float* fc_w  = (const float*)d_in[1];
    const float* fc_b  = (const float*)d_in[2];
    const float* cent  = (const float*)d_in[3];
    float* out = (float*)d_out;

    char* ws = (char*)d_ws;
    __half* softp = (__half*)ws;                         // 32 MB
    const size_t OFF = (size_t)N_ * K_ * S_ * sizeof(__half);
    float* a_sum = (float*)(ws + OFF);                   // 4 KB
    float* vlad  = (float*)(ws + OFF + 4096);            // 512 KB

    // zero the accumulators (soft' is fully overwritten, no init needed)
    hipMemsetAsync(ws + OFF, 0, 4096 + (size_t)N_ * K_ * C_ * sizeof(float), stream);

    softassign_kernel<<<N_ * S_ / 128, 128, 0, stream>>>(x, fc_w, fc_b, softp, a_sum);
    vlad_kernel<<<N_ * 32, 128, 0, stream>>>(x, softp, vlad);
    finalize_kernel<<<N_, 256, 0, stream>>>(vlad, a_sum, cent, out);
}

// Round 2
// 180.571 us; speedup vs baseline: 1.6720x; 1.6720x over previous
//
#include <hip/hip_runtime.h>
#include <hip/hip_fp16.h>

#define N_ 16
#define C_ 128
#define S_ 16384
#define K_ 64

// ---------------------------------------------------------------------------
// K2 v2: LDS-tiled logits GEMM + softmax. Block = 256 threads, one n-chunk of
// 512 positions, 8 tiles of 64 s. W staged once/block. Thread owns 4k x 4s
// (k strided 16 -> softmax reduce = shfl_xor over 16 lanes).
// soft' = softmax * (1/||x||) written fp16; a_sum accumulated via atomics.
// ---------------------------------------------------------------------------
__global__ __launch_bounds__(256) void softassign_kernel(
    const float* __restrict__ x, const float* __restrict__ fc_w,
    const float* __restrict__ fc_b, __half* __restrict__ softp,
    float* __restrict__ a_sum)
{
    __shared__ __align__(16) float wt[K_][132];   // 33.8 KB, pad: 2-way reads
    __shared__ __align__(16) float xt[C_][68];    // 34.8 KB, natural [c][s]
    __shared__ float rns[64];
    const int tid = threadIdx.x;
    const int n = blockIdx.x >> 5;
    const int chunk = blockIdx.x & 31;

    // stage W once (float4 over c, coalesced)
#pragma unroll
    for (int r = 0; r < 8; ++r) {
        int idx = r * 256 + tid;          // float4 index, 2048 total
        int k = idx >> 5, c4 = idx & 31;  // 32 float4 per k-row
        *(float4*)&wt[k][c4 * 4] = *(const float4*)(fc_w + k * C_ + c4 * 4);
    }
    const int tk = tid & 15, ts = tid >> 4;
    float bias[4];
#pragma unroll
    for (int i = 0; i < 4; ++i) bias[i] = fc_b[tk + 16 * i];
    float a_acc[4] = {0.f, 0.f, 0.f, 0.f};
    const float* xb = x + (size_t)n * C_ * S_;
    __half* sb = softp + (size_t)n * K_ * S_;

#pragma unroll 1
    for (int t = 0; t < 8; ++t) {
        const int s0 = chunk * 512 + t * 64;
        __syncthreads();   // prev tile consumed (also orders W-stage at t=0)
        // stage x tile [128c][64s]: float4 over s, coalesced, b128 LDS writes
#pragma unroll
        for (int r = 0; r < 8; ++r) {
            int idx = r * 256 + tid;
            int c = idx >> 4, s4 = idx & 15;   // 16 float4 per c-row
            *(float4*)&xt[c][s4 * 4] =
                *(const float4*)(xb + (size_t)c * S_ + s0 + s4 * 4);
        }
        __syncthreads();
        // column norms: 4 threads per s, each sums 32 c
        {
            int sx = tid >> 2, q = tid & 3;
            float nacc = 0.f;
#pragma unroll
            for (int cc = 0; cc < 32; ++cc) {
                float v = xt[q * 32 + cc][sx];
                nacc += v * v;
            }
            nacc += __shfl_xor(nacc, 1);
            nacc += __shfl_xor(nacc, 2);
            if (q == 0) rns[sx] = 1.0f / fmaxf(sqrtf(nacc), 1e-12f);
        }
        __syncthreads();

        // GEMM: acc[i][j] = sum_c W[tk+16i][c] * x[c][ts*4+j]
        float acc[4][4];
#pragma unroll
        for (int i = 0; i < 4; ++i)
#pragma unroll
            for (int j = 0; j < 4; ++j) acc[i][j] = 0.f;

#pragma unroll
        for (int c4 = 0; c4 < 32; ++c4) {
            float4 wv[4], xv[4];
#pragma unroll
            for (int i = 0; i < 4; ++i)
                wv[i] = *(const float4*)&wt[tk + 16 * i][c4 * 4];
#pragma unroll
            for (int cc = 0; cc < 4; ++cc)
                xv[cc] = *(const float4*)&xt[c4 * 4 + cc][ts * 4];
#define FMA_COL(i, j, comp)                                                   \
            acc[i][j] += wv[i].x * xv[0].comp;                                \
            acc[i][j] += wv[i].y * xv[1].comp;                                \
            acc[i][j] += wv[i].z * xv[2].comp;                                \
            acc[i][j] += wv[i].w * xv[3].comp;
#pragma unroll
            for (int i = 0; i < 4; ++i) {
                FMA_COL(i, 0, x) FMA_COL(i, 1, y) FMA_COL(i, 2, z) FMA_COL(i, 3, w)
            }
#undef FMA_COL
        }

        // softmax over k (16 tk lanes x 4 local)
        float rn4[4];
#pragma unroll
        for (int j = 0; j < 4; ++j) rn4[j] = rns[ts * 4 + j];
        float mx[4], sm[4];
#pragma unroll
        for (int j = 0; j < 4; ++j) {
#pragma unroll
            for (int i = 0; i < 4; ++i)
                acc[i][j] = acc[i][j] * rn4[j] + bias[i];
            mx[j] = fmaxf(fmaxf(acc[0][j], acc[1][j]), fmaxf(acc[2][j], acc[3][j]));
            mx[j] = fmaxf(mx[j], __shfl_xor(mx[j], 1));
            mx[j] = fmaxf(mx[j], __shfl_xor(mx[j], 2));
            mx[j] = fmaxf(mx[j], __shfl_xor(mx[j], 4));
            mx[j] = fmaxf(mx[j], __shfl_xor(mx[j], 8));
            sm[j] = 0.f;
#pragma unroll
            for (int i = 0; i < 4; ++i) {
                acc[i][j] = __expf(acc[i][j] - mx[j]);
                sm[j] += acc[i][j];
            }
            sm[j] += __shfl_xor(sm[j], 1);
            sm[j] += __shfl_xor(sm[j], 2);
            sm[j] += __shfl_xor(sm[j], 4);
            sm[j] += __shfl_xor(sm[j], 8);
        }
        float binv[4], ainv[4];
#pragma unroll
        for (int j = 0; j < 4; ++j) {
            binv[j] = 1.0f / sm[j];
            ainv[j] = binv[j] * rn4[j];
        }
#pragma unroll
        for (int i = 0; i < 4; ++i) {
            a_acc[i] += (acc[i][0] * binv[0] + acc[i][1] * binv[1]) +
                        (acc[i][2] * binv[2] + acc[i][3] * binv[3]);
            union { __half2 h[2]; uint2 u; } pk;
            pk.h[0] = __floats2half2_rn(acc[i][0] * ainv[0], acc[i][1] * ainv[1]);
            pk.h[1] = __floats2half2_rn(acc[i][2] * ainv[2], acc[i][3] * ainv[3]);
            *(uint2*)(sb + (size_t)(tk + 16 * i) * S_ + s0 + ts * 4) = pk.u;
        }
    }
    // a_sum: sum over s -> reduce 4 in-wave ts groups, one lane-set adds
#pragma unroll
    for (int i = 0; i < 4; ++i) {
        a_acc[i] += __shfl_xor(a_acc[i], 16);
        a_acc[i] += __shfl_xor(a_acc[i], 32);
    }
    if ((tid & 63) < 16) {
#pragma unroll
        for (int i = 0; i < 4; ++i)
            atomicAdd(a_sum + n * K_ + tk + 16 * i, a_acc[i]);
    }
}

// ---------------------------------------------------------------------------
// K3: vlad[n,k,c] += sum_s soft'[k,s] * x_raw[c,s].  (unchanged)
// ---------------------------------------------------------------------------
__global__ __launch_bounds__(128) void vlad_kernel(
    const float* __restrict__ x, const __half* __restrict__ softp,
    float* __restrict__ vlad_acc)
{
    __shared__ __align__(16) float st[K_][36];
    __shared__ __align__(16) float xt[C_][36];
    const int tid = threadIdx.x;
    const int NCH = 32;
    const int n = blockIdx.x / NCH;
    const int chunk = blockIdx.x % NCH;
    const int SCH = S_ / NCH;
    const int sbase = chunk * SCH;
    const int kt = tid >> 4;
    const int ct = tid & 15;

    float acc[8][8];
#pragma unroll
    for (int i = 0; i < 8; ++i)
#pragma unroll
        for (int j = 0; j < 8; ++j) acc[i][j] = 0.f;

    const float* xbase = x + (size_t)n * C_ * S_;
    const __half* sbase_p = softp + (size_t)n * K_ * S_;

#pragma unroll 1
    for (int sub = 0; sub < SCH / 32; ++sub) {
        const int s0 = sbase + sub * 32;
#pragma unroll
        for (int j = 0; j < 32; ++j) {
            int idx = j * 128 + tid;
            int c = idx >> 5, sl = idx & 31;
            xt[c][sl] = xbase[(size_t)c * S_ + s0 + sl];
        }
#pragma unroll
        for (int j = 0; j < 16; ++j) {
            int idx = j * 128 + tid;
            int k = idx >> 5, sl = idx & 31;
            st[k][sl] = __half2float(sbase_p[(size_t)k * S_ + s0 + sl]);
        }
        __syncthreads();

#pragma unroll
        for (int r = 0; r < 8; ++r) {
            const int sl4 = ((r + kt) & 7) * 4;
            float4 sv[8], xv[8];
#pragma unroll
            for (int i = 0; i < 8; ++i)
                sv[i] = *(const float4*)&st[kt * 8 + i][sl4];
#pragma unroll
            for (int j = 0; j < 8; ++j)
                xv[j] = *(const float4*)&xt[ct + 16 * j][sl4];
#pragma unroll
            for (int i = 0; i < 8; ++i)
#pragma unroll
                for (int j = 0; j < 8; ++j) {
                    acc[i][j] += sv[i].x * xv[j].x;
                    acc[i][j] += sv[i].y * xv[j].y;
                    acc[i][j] += sv[i].z * xv[j].z;
                    acc[i][j] += sv[i].w * xv[j].w;
                }
        }
        __syncthreads();
    }

    float* vp = vlad_acc + (size_t)n * K_ * C_;
#pragma unroll
    for (int i = 0; i < 8; ++i)
#pragma unroll
        for (int j = 0; j < 8; ++j)
            atomicAdd(vp + (kt * 8 + i) * C_ + ct + 16 * j, acc[i][j]);
}

// ---------------------------------------------------------------------------
// K4: finalize (unchanged)
// ---------------------------------------------------------------------------
__global__ __launch_bounds__(256) void finalize_kernel(
    const float* __restrict__ vlad_acc, const float* __restrict__ a_sum,
    const float* __restrict__ centroids, float* __restrict__ out)
{
    __shared__ float red[4];
    const int n = blockIdx.x;
    const int t = threadIdx.x;
    const int k = t >> 2, q = t & 3;
    const float av = a_sum[n * K_ + k];
    const float* vp = vlad_acc + ((size_t)n * K_ + k) * C_;
    const float* cp = centroids + k * C_;

    float v[32];
    float ssq = 0.f;
#pragma unroll
    for (int j = 0; j < 32; ++j) {
        int c = q + 4 * j;
        float val = vp[c] - av * cp[c];
        v[j] = val;
        ssq += val * val;
    }
    ssq += __shfl_xor(ssq, 1);
    ssq += __shfl_xor(ssq, 2);
    const float inv1 = 1.0f / fmaxf(sqrtf(ssq), 1e-12f);

    float gp = (q == 0) ? ssq * inv1 * inv1 : 0.f;
#pragma unroll
    for (int off = 1; off < 64; off <<= 1) gp += __shfl_xor(gp, off);
    if ((t & 63) == 0) red[t >> 6] = gp;
    __syncthreads();
    const float G = red[0] + red[1] + red[2] + red[3];
    const float ginv = 1.0f / fmaxf(sqrtf(G), 1e-12f);

    float* op = out + (size_t)n * (K_ * C_) + k * C_;
#pragma unroll
    for (int j = 0; j < 32; ++j) op[q + 4 * j] = v[j] * inv1 * ginv;
}

extern "C" void kernel_launch(void* const* d_in, const int* in_sizes, int n_in,
                              void* d_out, int out_size, void* d_ws, size_t ws_size,
                              hipStream_t stream) {
    const float* x     = (const float*)d_in[0];
    const float* fc_w  = (const float*)d_in[1];
    const float* fc_b  = (const float*)d_in[2];
    const float* cent  = (const float*)d_in[3];
    float* out = (float*)d_out;

    char* ws = (char*)d_ws;
    __half* softp = (__half*)ws;                         // 32 MB
    const size_t OFF = (size_t)N_ * K_ * S_ * sizeof(__half);
    float* a_sum = (float*)(ws + OFF);                   // 4 KB
    float* vlad  = (float*)(ws + OFF + 4096);            // 512 KB

    hipMemsetAsync(ws + OFF, 0, 4096 + (size_t)N_ * K_ * C_ * sizeof(float), stream);

    softassign_kernel<<<N_ * 32, 256, 0, stream>>>(x, fc_w, fc_b, softp, a_sum);
    vlad_kernel<<<N_ * 32, 128, 0, stream>>>(x, softp, vlad);
    finalize_kernel<<<N_, 256, 0, stream>>>(vlad, a_sum, cent, out);
}

// Round 3
// 172.324 us; speedup vs baseline: 1.7520x; 1.0479x over previous
//
#include <hip/hip_runtime.h>
#include <hip/hip_fp16.h>

#define N_ 16
#define C_ 128
#define S_ 16384
#define K_ 64

typedef __attribute__((ext_vector_type(4))) float f32x4;
typedef __attribute__((ext_vector_type(8))) _Float16 f16x8;
typedef __attribute__((ext_vector_type(4))) _Float16 f16x4;

// ---------------------------------------------------------------------------
// K2 v3: logits GEMM on MFMA (f16, W hi/lo split), in-register softmax.
// Block = 256 thr (4 waves), one 128-s tile. A = xT[s][c], B = W[k][c],
// D[s][k] per 16x16x32: lane&15 = k, rows (lane>>4)*4+r = s-local.
// Wave w owns m-tiles {w, w+4} (s in [16w,16w+16) and [64+16w, 64+16w+16)).
// All LDS rows 256B (128 f16) with XOR swizzle: elem ^= ((row&7)<<3).
// ---------------------------------------------------------------------------
__global__ __launch_bounds__(256, 2) void softassign_mfma(
    const float* __restrict__ x, const float* __restrict__ fc_w,
    const float* __restrict__ fc_b, __half* __restrict__ softp,
    float* __restrict__ a_sum)
{
    __shared__ _Float16 xT[128 * 128];   // 32 KB  [s][c] f16 swz
    __shared__ _Float16 Wh[64 * 128];    // 16 KB  [k][c] f16 swz
    __shared__ _Float16 Wl[64 * 128];    // 16 KB
    __shared__ _Float16 sst[64 * 64];    //  8 KB  [k][s-half] swz (<<3 on 8-elem granule? see below)
    __shared__ float rns[128];

    const int tid  = threadIdx.x;
    const int n     = blockIdx.x >> 7;
    const int chunk = blockIdx.x & 127;
    const int s0    = chunk * 128;
    const int lane = tid & 63, w = tid >> 6;
    const int lr = lane & 15, g = lane >> 4;

    if (tid < 128) rns[tid] = 0.f;

    // ---- stage W hi/lo: 8 float4 per thread ----
#pragma unroll
    for (int i = 0; i < 8; ++i) {
        int idx = i * 256 + tid;
        int c4 = idx & 31, k = idx >> 5;
        float4 wv = *(const float4*)(fc_w + k * C_ + c4 * 4);
        _Float16 h0 = (_Float16)wv.x, h1 = (_Float16)wv.y,
                 h2 = (_Float16)wv.z, h3 = (_Float16)wv.w;
        f16x4 hi = {h0, h1, h2, h3};
        f16x4 lo = {(_Float16)(wv.x - (float)h0), (_Float16)(wv.y - (float)h1),
                    (_Float16)(wv.z - (float)h2), (_Float16)(wv.w - (float)h3)};
        int e = k * 128 + ((c4 * 4) ^ ((k & 7) << 3));
        *(f16x4*)&Wh[e] = hi;
        *(f16x4*)&Wl[e] = lo;
    }
    __syncthreads();   // rns zeroed before atomics; W ordered by later barriers

    // ---- stage xT (in-register 4x4 transpose) + norm partials ----
    {
        const int s4 = tid & 31;                    // s-quad, fixed across iters
        float part[4] = {0.f, 0.f, 0.f, 0.f};
#pragma unroll
        for (int i = 0; i < 4; ++i) {
            int cq = ((i * 256 + tid) >> 5);        // c-quad 0..31
            float4 xv[4];
#pragma unroll
            for (int cc = 0; cc < 4; ++cc)
                xv[cc] = *(const float4*)(x + (size_t)n * C_ * S_ +
                                          (size_t)(cq * 4 + cc) * S_ + s0 + s4 * 4);
#pragma unroll
            for (int j = 0; j < 4; ++j) {
                float v0 = (&xv[0].x)[j], v1 = (&xv[1].x)[j],
                      v2 = (&xv[2].x)[j], v3 = (&xv[3].x)[j];
                part[j] += v0 * v0 + v1 * v1 + v2 * v2 + v3 * v3;
                f16x4 p = {(_Float16)v0, (_Float16)v1, (_Float16)v2, (_Float16)v3};
                int s = s4 * 4 + j;
                *(f16x4*)&xT[s * 128 + ((cq * 4) ^ ((s & 7) << 3))] = p;
            }
        }
#pragma unroll
        for (int j = 0; j < 4; ++j) atomicAdd(&rns[s4 * 4 + j], part[j]);
    }
    __syncthreads();
    if (tid < 128) rns[tid] = 1.0f / fmaxf(sqrtf(rns[tid]), 1e-12f);
    __syncthreads();

    // ---- GEMM: acc[h][nt] over 4 k-steps, hi+lo ----
    f32x4 acc[2][4];
#pragma unroll
    for (int h = 0; h < 2; ++h)
#pragma unroll
        for (int nt = 0; nt < 4; ++nt) acc[h][nt] = (f32x4){0.f, 0.f, 0.f, 0.f};

#pragma unroll
    for (int kt = 0; kt < 4; ++kt) {
        const int c = kt * 32 + g * 8;
        f16x8 af[2], whf[4], wlf[4];
#pragma unroll
        for (int h = 0; h < 2; ++h) {
            int s = h * 64 + w * 16 + lr;
            af[h] = *(const f16x8*)&xT[s * 128 + (c ^ ((s & 7) << 3))];
        }
#pragma unroll
        for (int nt = 0; nt < 4; ++nt) {
            int k = nt * 16 + lr;
            int e = k * 128 + (c ^ ((k & 7) << 3));
            whf[nt] = *(const f16x8*)&Wh[e];
            wlf[nt] = *(const f16x8*)&Wl[e];
        }
#pragma unroll
        for (int h = 0; h < 2; ++h)
#pragma unroll
            for (int nt = 0; nt < 4; ++nt) {
                acc[h][nt] = __builtin_amdgcn_mfma_f32_16x16x32_f16(af[h], whf[nt], acc[h][nt], 0, 0, 0);
                acc[h][nt] = __builtin_amdgcn_mfma_f32_16x16x32_f16(af[h], wlf[nt], acc[h][nt], 0, 0, 0);
            }
    }

    // ---- softmax (over k: 4 nt regs x 16 lr lanes), write soft', a_sum ----
    float bias[4];
#pragma unroll
    for (int nt = 0; nt < 4; ++nt) bias[nt] = fc_b[nt * 16 + lr];
    float aacc[4] = {0.f, 0.f, 0.f, 0.f};

#pragma unroll
    for (int h = 0; h < 2; ++h) {
        float rnl[4];
#pragma unroll
        for (int r = 0; r < 4; ++r) rnl[r] = rns[h * 64 + w * 16 + g * 4 + r];
#pragma unroll
        for (int nt = 0; nt < 4; ++nt)
#pragma unroll
            for (int r = 0; r < 4; ++r)
                acc[h][nt][r] = __expf(acc[h][nt][r] * rnl[r] + bias[nt]);
        float ai[4];
#pragma unroll
        for (int r = 0; r < 4; ++r) {
            float sum = (acc[h][0][r] + acc[h][1][r]) + (acc[h][2][r] + acc[h][3][r]);
            sum += __shfl_xor(sum, 1);
            sum += __shfl_xor(sum, 2);
            sum += __shfl_xor(sum, 4);
            sum += __shfl_xor(sum, 8);
            float bi = 1.0f / sum;
            ai[r] = bi * rnl[r];
#pragma unroll
            for (int nt = 0; nt < 4; ++nt) aacc[nt] += acc[h][nt][r] * bi;
        }
        // stage soft' tile [64k][64s] (swz) then coalesced copy-out
#pragma unroll
        for (int nt = 0; nt < 4; ++nt) {
            int k = nt * 16 + lr;
            int sloc = w * 16 + g * 4;
            f16x4 p = {(_Float16)(acc[h][nt][0] * ai[0]), (_Float16)(acc[h][nt][1] * ai[1]),
                       (_Float16)(acc[h][nt][2] * ai[2]), (_Float16)(acc[h][nt][3] * ai[3])};
            *(f16x4*)&sst[k * 64 + (sloc ^ ((k & 7) << 3))] = p;
        }
        __syncthreads();
#pragma unroll
        for (int i = 0; i < 2; ++i) {
            int idx = i * 256 + tid;
            int kk = idx >> 3, sl = idx & 7;
            f16x8 v = *(const f16x8*)&sst[kk * 64 + ((sl * 8) ^ ((kk & 7) << 3))];
            *(f16x8*)((__half*)softp + (size_t)(n * K_ + kk) * S_ + s0 + h * 64 + sl * 8) = v;
        }
        __syncthreads();
    }
    // a_sum reduce over g-groups, one lane-set adds
#pragma unroll
    for (int nt = 0; nt < 4; ++nt) {
        aacc[nt] += __shfl_xor(aacc[nt], 16);
        aacc[nt] += __shfl_xor(aacc[nt], 32);
    }
    if (lane < 16) {
#pragma unroll
        for (int nt = 0; nt < 4; ++nt)
            atomicAdd(a_sum + n * K_ + nt * 16 + lr, aacc[nt]);
    }
}

// ---------------------------------------------------------------------------
// K3: vlad[n,k,c] += sum_s soft'[k,s] * x_raw[c,s].  (unchanged)
// ---------------------------------------------------------------------------
__global__ __launch_bounds__(128) void vlad_kernel(
    const float* __restrict__ x, const __half* __restrict__ softp,
    float* __restrict__ vlad_acc)
{
    __shared__ __align__(16) float st[K_][36];
    __shared__ __align__(16) float xt[C_][36];
    const int tid = threadIdx.x;
    const int NCH = 32;
    const int n = blockIdx.x / NCH;
    const int chunk = blockIdx.x % NCH;
    const int SCH = S_ / NCH;
    const int sbase = chunk * SCH;
    const int kt = tid >> 4;
    const int ct = tid & 15;

    float acc[8][8];
#pragma unroll
    for (int i = 0; i < 8; ++i)
#pragma unroll
        for (int j = 0; j < 8; ++j) acc[i][j] = 0.f;

    const float* xbase = x + (size_t)n * C_ * S_;
    const __half* sbase_p = softp + (size_t)n * K_ * S_;

#pragma unroll 1
    for (int sub = 0; sub < SCH / 32; ++sub) {
        const int s0 = sbase + sub * 32;
#pragma unroll
        for (int j = 0; j < 32; ++j) {
            int idx = j * 128 + tid;
            int c = idx >> 5, sl = idx & 31;
            xt[c][sl] = xbase[(size_t)c * S_ + s0 + sl];
        }
#pragma unroll
        for (int j = 0; j < 16; ++j) {
            int idx = j * 128 + tid;
            int k = idx >> 5, sl = idx & 31;
            st[k][sl] = __half2float(sbase_p[(size_t)k * S_ + s0 + sl]);
        }
        __syncthreads();

#pragma unroll
        for (int r = 0; r < 8; ++r) {
            const int sl4 = ((r + kt) & 7) * 4;
            float4 sv[8], xv[8];
#pragma unroll
            for (int i = 0; i < 8; ++i)
                sv[i] = *(const float4*)&st[kt * 8 + i][sl4];
#pragma unroll
            for (int j = 0; j < 8; ++j)
                xv[j] = *(const float4*)&xt[ct + 16 * j][sl4];
#pragma unroll
            for (int i = 0; i < 8; ++i)
#pragma unroll
                for (int j = 0; j < 8; ++j) {
                    acc[i][j] += sv[i].x * xv[j].x;
                    acc[i][j] += sv[i].y * xv[j].y;
                    acc[i][j] += sv[i].z * xv[j].z;
                    acc[i][j] += sv[i].w * xv[j].w;
                }
        }
        __syncthreads();
    }

    float* vp = vlad_acc + (size_t)n * K_ * C_;
#pragma unroll
    for (int i = 0; i < 8; ++i)
#pragma unroll
        for (int j = 0; j < 8; ++j)
            atomicAdd(vp + (kt * 8 + i) * C_ + ct + 16 * j, acc[i][j]);
}

// ---------------------------------------------------------------------------
// K4: finalize (unchanged)
// ---------------------------------------------------------------------------
__global__ __launch_bounds__(256) void finalize_kernel(
    const float* __restrict__ vlad_acc, const float* __restrict__ a_sum,
    const float* __restrict__ centroids, float* __restrict__ out)
{
    __shared__ float red[4];
    const int n = blockIdx.x;
    const int t = threadIdx.x;
    const int k = t >> 2, q = t & 3;
    const float av = a_sum[n * K_ + k];
    const float* vp = vlad_acc + ((size_t)n * K_ + k) * C_;
    const float* cp = centroids + k * C_;

    float v[32];
    float ssq = 0.f;
#pragma unroll
    for (int j = 0; j < 32; ++j) {
        int c = q + 4 * j;
        float val = vp[c] - av * cp[c];
        v[j] = val;
        ssq += val * val;
    }
    ssq += __shfl_xor(ssq, 1);
    ssq += __shfl_xor(ssq, 2);
    const float inv1 = 1.0f / fmaxf(sqrtf(ssq), 1e-12f);

    float gp = (q == 0) ? ssq * inv1 * inv1 : 0.f;
#pragma unroll
    for (int off = 1; off < 64; off <<= 1) gp += __shfl_xor(gp, off);
    if ((t & 63) == 0) red[t >> 6] = gp;
    __syncthreads();
    const float G = red[0] + red[1] + red[2] + red[3];
    const float ginv = 1.0f / fmaxf(sqrtf(G), 1e-12f);

    float* op = out + (size_t)n * (K_ * C_) + k * C_;
#pragma unroll
    for (int j = 0; j < 32; ++j) op[q + 4 * j] = v[j] * inv1 * ginv;
}

extern "C" void kernel_launch(void* const* d_in, const int* in_sizes, int n_in,
                              void* d_out, int out_size, void* d_ws, size_t ws_size,
                              hipStream_t stream) {
    const float* x     = (const float*)d_in[0];
    const float* fc_w  = (const float*)d_in[1];
    const float* fc_b  = (const float*)d_in[2];
    const float* cent  = (const float*)d_in[3];
    float* out = (float*)d_out;

    char* ws = (char*)d_ws;
    __half* softp = (__half*)ws;                         // 32 MB
    const size_t OFF = (size_t)N_ * K_ * S_ * sizeof(__half);
    float* a_sum = (float*)(ws + OFF);                   // 4 KB
    float* vlad  = (float*)(ws + OFF + 4096);            // 512 KB

    hipMemsetAsync(ws + OFF, 0, 4096 + (size_t)N_ * K_ * C_ * sizeof(float), stream);

    softassign_mfma<<<N_ * 128, 256, 0, stream>>>(x, fc_w, fc_b, softp, a_sum);
    vlad_kernel<<<N_ * 32, 128, 0, stream>>>(x, softp, vlad);
    finalize_kernel<<<N_, 256, 0, stream>>>(vlad, a_sum, cent, out);
}

// Round 4
// 79.937 us; speedup vs baseline: 3.7769x; 2.1557x over previous
//
#include <hip/hip_runtime.h>
#include <hip/hip_fp16.h>

#define N_ 16
#define C_ 128
#define S_ 16384
#define K_ 64

typedef __attribute__((ext_vector_type(4))) float f32x4;
typedef __attribute__((ext_vector_type(8))) _Float16 f16x8;
typedef __attribute__((ext_vector_type(4))) _Float16 f16x4;

// xT row-swizzle: varies with s4 on staging writes (rows s=4*s4+j) AND with
// lr on fragment reads (rows s=16m+lr) -> ~2-way writes, uniform reads.
#define SWZ_S(s) ((((s) ^ ((s) >> 3)) & 7) << 3)

// ---------------------------------------------------------------------------
// Fused: logits MFMA -> softmax (in-register) -> vlad MFMA. x read ONCE.
// Block 256 thr (4 waves), 1 block/CU (116 KB LDS). Each block: one n,
// one 512-s chunk = 4 tiles of 128 s. vlad partials held in VGPRs across
// tiles, atomic-flushed once. soft' never goes to global.
// Logits GEMM: D[s][k], A=xT[s][c] (c-contig), B=Wh/Wl[k][c] (c-contig).
// Vlad  GEMM: D[k][c], A=sst[k][s] (s-contig), B=xC[c][s] (s-contig).
// ---------------------------------------------------------------------------
__global__ __launch_bounds__(256, 1) void fused_kernel(
    const float* __restrict__ x, const float* __restrict__ fc_w,
    const float* __restrict__ fc_b, float* __restrict__ vlad_acc,
    float* __restrict__ a_sum)
{
    __shared__ _Float16 xT[128 * 128];   // 32 KB [s][c]
    __shared__ _Float16 xC[128 * 128];   // 32 KB [c][s]
    __shared__ _Float16 Wh[64 * 128];    // 16 KB [k][c]
    __shared__ _Float16 Wl[64 * 128];    // 16 KB
    __shared__ _Float16 sst[64 * 128];   // 16 KB [k][s]
    __shared__ float rns[4][128];        //  2 KB per-tile ssq

    const int tid = threadIdx.x;
    const int n = blockIdx.x >> 5;
    const int chunk = blockIdx.x & 31;
    const int lane = tid & 63, w = tid >> 6;
    const int lr = lane & 15, g = lane >> 4;
    const int fsw = (lr & 7) << 3;       // swizzle for all rows of form m*16+lr

    // ---- stage W hi/lo (once) ----
#pragma unroll
    for (int i = 0; i < 8; ++i) {
        int idx = i * 256 + tid;
        int c4 = idx & 31, k = idx >> 5;
        float4 wv = *(const float4*)(fc_w + k * C_ + c4 * 4);
        _Float16 h0 = (_Float16)wv.x, h1 = (_Float16)wv.y,
                 h2 = (_Float16)wv.z, h3 = (_Float16)wv.w;
        f16x4 hi = {h0, h1, h2, h3};
        f16x4 lo = {(_Float16)(wv.x - (float)h0), (_Float16)(wv.y - (float)h1),
                    (_Float16)(wv.z - (float)h2), (_Float16)(wv.w - (float)h3)};
        int e = k * 128 + ((c4 * 4) ^ ((k & 7) << 3));
        *(f16x4*)&Wh[e] = hi;
        *(f16x4*)&Wl[e] = lo;
    }
    if (tid < 128) {
#pragma unroll
        for (int t = 0; t < 4; ++t) rns[t][tid] = 0.f;
    }

    float bias[4];
#pragma unroll
    for (int nt = 0; nt < 4; ++nt) bias[nt] = fc_b[nt * 16 + lr];
    float a_acc[4] = {0.f, 0.f, 0.f, 0.f};
    f32x4 vacc[8];
#pragma unroll
    for (int nt = 0; nt < 8; ++nt) vacc[nt] = (f32x4){0.f, 0.f, 0.f, 0.f};

    const float* xb = x + (size_t)n * C_ * S_;
    const int s4 = tid & 31;
    int cqv[4];
#pragma unroll
    for (int i = 0; i < 4; ++i) cqv[i] = (i * 256 + tid) >> 5;

    // prefetch tile 0 into registers
    float4 pre[4][4];
#pragma unroll
    for (int i = 0; i < 4; ++i)
#pragma unroll
        for (int cc = 0; cc < 4; ++cc)
            pre[i][cc] = *(const float4*)(xb + (size_t)(cqv[i] * 4 + cc) * S_ +
                                          chunk * 512 + s4 * 4);

#pragma unroll 1
    for (int t = 0; t < 4; ++t) {
        __syncthreads();   // prev tile's LDS fully consumed (W/rns ready at t=0)
        // ---- stage writes from regs: xT (transpose) + xC + norm partials ----
        float part[4] = {0.f, 0.f, 0.f, 0.f};
#pragma unroll
        for (int i = 0; i < 4; ++i) {
            int cq = cqv[i];
#pragma unroll
            for (int j = 0; j < 4; ++j) {
                float v0 = (&pre[i][0].x)[j], v1 = (&pre[i][1].x)[j],
                      v2 = (&pre[i][2].x)[j], v3 = (&pre[i][3].x)[j];
                part[j] += v0 * v0 + v1 * v1 + v2 * v2 + v3 * v3;
                f16x4 p = {(_Float16)v0, (_Float16)v1, (_Float16)v2, (_Float16)v3};
                int s = s4 * 4 + j;
                *(f16x4*)&xT[s * 128 + ((cq * 4) ^ SWZ_S(s))] = p;
            }
#pragma unroll
            for (int cc = 0; cc < 4; ++cc) {
                int c = cq * 4 + cc;
                f16x4 q = {(_Float16)pre[i][cc].x, (_Float16)pre[i][cc].y,
                           (_Float16)pre[i][cc].z, (_Float16)pre[i][cc].w};
                *(f16x4*)&xC[c * 128 + ((s4 * 4) ^ ((c & 7) << 3))] = q;
            }
        }
#pragma unroll
        for (int j = 0; j < 4; ++j) atomicAdd(&rns[t][s4 * 4 + j], part[j]);
        // issue next tile's loads (regs only, no LDS hazard) under GEMM phase
        if (t < 3) {
#pragma unroll
            for (int i = 0; i < 4; ++i)
#pragma unroll
                for (int cc = 0; cc < 4; ++cc)
                    pre[i][cc] = *(const float4*)(xb + (size_t)(cqv[i] * 4 + cc) * S_ +
                                                  chunk * 512 + (t + 1) * 128 + s4 * 4);
        }
        __syncthreads();

        // ---- logits GEMM: D[s][k], wave w owns s-tiles {w, w+4} ----
        f32x4 acc[2][4];
#pragma unroll
        for (int h = 0; h < 2; ++h)
#pragma unroll
            for (int nt = 0; nt < 4; ++nt) acc[h][nt] = (f32x4){0.f, 0.f, 0.f, 0.f};
#pragma unroll
        for (int kt = 0; kt < 4; ++kt) {
            const int co = kt * 32 + g * 8;
            f16x8 af[2], whf[4], wlf[4];
#pragma unroll
            for (int h = 0; h < 2; ++h) {
                int s = h * 64 + w * 16 + lr;
                af[h] = *(const f16x8*)&xT[s * 128 + (co ^ SWZ_S(s))];
            }
#pragma unroll
            for (int nt = 0; nt < 4; ++nt) {
                int e = (nt * 16 + lr) * 128 + (co ^ fsw);
                whf[nt] = *(const f16x8*)&Wh[e];
                wlf[nt] = *(const f16x8*)&Wl[e];
            }
#pragma unroll
            for (int h = 0; h < 2; ++h)
#pragma unroll
                for (int nt = 0; nt < 4; ++nt) {
                    acc[h][nt] = __builtin_amdgcn_mfma_f32_16x16x32_f16(af[h], whf[nt], acc[h][nt], 0, 0, 0);
                    acc[h][nt] = __builtin_amdgcn_mfma_f32_16x16x32_f16(af[h], wlf[nt], acc[h][nt], 0, 0, 0);
                }
        }

        // ---- softmax over k (4 nt regs x 16 lr lanes), soft' -> sst ----
#pragma unroll
        for (int h = 0; h < 2; ++h) {
            float rnl[4];
#pragma unroll
            for (int r = 0; r < 4; ++r) {
                float ss = rns[t][h * 64 + w * 16 + g * 4 + r];
                rnl[r] = 1.0f / fmaxf(sqrtf(ss), 1e-12f);
            }
#pragma unroll
            for (int nt = 0; nt < 4; ++nt)
#pragma unroll
                for (int r = 0; r < 4; ++r)
                    acc[h][nt][r] = __expf(acc[h][nt][r] * rnl[r] + bias[nt]);
            float ai[4];
#pragma unroll
            for (int r = 0; r < 4; ++r) {
                float sum = (acc[h][0][r] + acc[h][1][r]) + (acc[h][2][r] + acc[h][3][r]);
                sum += __shfl_xor(sum, 1);
                sum += __shfl_xor(sum, 2);
                sum += __shfl_xor(sum, 4);
                sum += __shfl_xor(sum, 8);
                float bi = 1.0f / sum;
                ai[r] = bi * rnl[r];
#pragma unroll
                for (int nt = 0; nt < 4; ++nt) a_acc[nt] += acc[h][nt][r] * bi;
            }
#pragma unroll
            for (int nt = 0; nt < 4; ++nt) {
                int k = nt * 16 + lr;
                int sloc = h * 64 + w * 16 + g * 4;
                f16x4 p = {(_Float16)(acc[h][nt][0] * ai[0]), (_Float16)(acc[h][nt][1] * ai[1]),
                           (_Float16)(acc[h][nt][2] * ai[2]), (_Float16)(acc[h][nt][3] * ai[3])};
                *(f16x4*)&sst[k * 128 + (sloc ^ fsw)] = p;
            }
        }
        __syncthreads();

        // ---- vlad GEMM: D[k][c], wave w owns k-tile w; accumulate in vacc ----
#pragma unroll
        for (int kt = 0; kt < 4; ++kt) {
            const int so = kt * 32 + g * 8;
            f16x8 pa = *(const f16x8*)&sst[(w * 16 + lr) * 128 + (so ^ fsw)];
#pragma unroll
            for (int nt = 0; nt < 8; ++nt) {
                f16x8 xv = *(const f16x8*)&xC[(nt * 16 + lr) * 128 + (so ^ fsw)];
                vacc[nt] = __builtin_amdgcn_mfma_f32_16x16x32_f16(pa, xv, vacc[nt], 0, 0, 0);
            }
        }
    }

    // ---- flush vlad partials + a_sum ----
    float* vp = vlad_acc + ((size_t)n * K_ + w * 16) * C_;
#pragma unroll
    for (int nt = 0; nt < 8; ++nt)
#pragma unroll
        for (int r = 0; r < 4; ++r)
            atomicAdd(vp + (g * 4 + r) * C_ + nt * 16 + lr, vacc[nt][r]);
#pragma unroll
    for (int nt = 0; nt < 4; ++nt) {
        a_acc[nt] += __shfl_xor(a_acc[nt], 16);
        a_acc[nt] += __shfl_xor(a_acc[nt], 32);
    }
    if (lane < 16) {
#pragma unroll
        for (int nt = 0; nt < 4; ++nt)
            atomicAdd(a_sum + n * K_ + nt * 16 + lr, a_acc[nt]);
    }
}

// ---------------------------------------------------------------------------
// Finalize: vlad -= a_sum*centroids; intra-norm over C; global norm.
// ---------------------------------------------------------------------------
__global__ __launch_bounds__(256) void finalize_kernel(
    const float* __restrict__ vlad_acc, const float* __restrict__ a_sum,
    const float* __restrict__ centroids, float* __restrict__ out)
{
    __shared__ float red[4];
    const int n = blockIdx.x;
    const int t = threadIdx.x;
    const int k = t >> 2, q = t & 3;
    const float av = a_sum[n * K_ + k];
    const float* vp = vlad_acc + ((size_t)n * K_ + k) * C_;
    const float* cp = centroids + k * C_;

    float v[32];
    float ssq = 0.f;
#pragma unroll
    for (int j = 0; j < 32; ++j) {
        int c = q + 4 * j;
        float val = vp[c] - av * cp[c];
        v[j] = val;
        ssq += val * val;
    }
    ssq += __shfl_xor(ssq, 1);
    ssq += __shfl_xor(ssq, 2);
    const float inv1 = 1.0f / fmaxf(sqrtf(ssq), 1e-12f);

    float gp = (q == 0) ? ssq * inv1 * inv1 : 0.f;
#pragma unroll
    for (int off = 1; off < 64; off <<= 1) gp += __shfl_xor(gp, off);
    if ((t & 63) == 0) red[t >> 6] = gp;
    __syncthreads();
    const float G = red[0] + red[1] + red[2] + red[3];
    const float ginv = 1.0f / fmaxf(sqrtf(G), 1e-12f);

    float* op = out + (size_t)n * (K_ * C_) + k * C_;
#pragma unroll
    for (int j = 0; j < 32; ++j) op[q + 4 * j] = v[j] * inv1 * ginv;
}

extern "C" void kernel_launch(void* const* d_in, const int* in_sizes, int n_in,
                              void* d_out, int out_size, void* d_ws, size_t ws_size,
                              hipStream_t stream) {
    const float* x     = (const float*)d_in[0];
    const float* fc_w  = (const float*)d_in[1];
    const float* fc_b  = (const float*)d_in[2];
    const float* cent  = (const float*)d_in[3];
    float* out = (float*)d_out;

    char* ws = (char*)d_ws;
    float* a_sum = (float*)ws;                 // 4 KB (N*K = 1024 floats)
    float* vlad  = (float*)(ws + 4096);        // 512 KB

    hipMemsetAsync(ws, 0, 4096 + (size_t)N_ * K_ * C_ * sizeof(float), stream);

    fused_kernel<<<N_ * 32, 256, 0, stream>>>(x, fc_w, fc_b, vlad, a_sum);
    finalize_kernel<<<N_, 256, 0, stream>>>(vlad, a_sum, cent, out);
}

// Round 5
// 60.386 us; speedup vs baseline: 4.9997x; 1.3238x over previous
//
#include <hip/hip_runtime.h>
#include <hip/hip_fp16.h>

#define N_ 16
#define C_ 128
#define S_ 16384
#define K_ 64

typedef __attribute__((ext_vector_type(4))) float f32x4;
typedef __attribute__((ext_vector_type(8))) _Float16 f16x8;
typedef __attribute__((ext_vector_type(4))) _Float16 f16x4;

// xT row-swizzle: varies with staging rows s=4*s4+j AND frag rows s=16m+lr.
#define SWZ_S(s) ((((s) ^ ((s) >> 3)) & 7) << 3)

// ---------------------------------------------------------------------------
// Fused v2: 64-s tiles (8 per block) -> 74 KB LDS -> 2 blocks/CU.
// Block 256 thr (4 waves), one n, one 512-s chunk. x read ONCE from HBM.
// Logits GEMM: D[s][k], A=xT[s][c], B=Wh/Wl[k][c] (hi/lo f16 split of W).
// Vlad  GEMM: D[k][c], A=sst[k][s], B=xC[c][s]; vacc held across tiles.
// ---------------------------------------------------------------------------
__global__ __launch_bounds__(256, 2) void fused_kernel(
    const float* __restrict__ x, const float* __restrict__ fc_w,
    const float* __restrict__ fc_b, float* __restrict__ vlad_acc,
    float* __restrict__ a_sum)
{
    __shared__ _Float16 xT[64 * 128];    // 16 KB [s][c]
    __shared__ _Float16 xC[128 * 64];    // 16 KB [c][s]
    __shared__ _Float16 Wh[64 * 128];    // 16 KB [k][c]
    __shared__ _Float16 Wl[64 * 128];    // 16 KB
    __shared__ _Float16 sst[64 * 64];    //  8 KB [k][s]
    __shared__ float rns[8][64];         //  2 KB per-tile col ssq

    const int tid = threadIdx.x;
    const int n = blockIdx.x >> 5;
    const int chunk = blockIdx.x & 31;
    const int lane = tid & 63, w = tid >> 6;
    const int lr = lane & 15, g = lane >> 4;
    const int fsw = (lr & 7) << 3;       // swizzle for rows of form m*16+lr

    // ---- stage W hi/lo (once) ----
#pragma unroll
    for (int i = 0; i < 8; ++i) {
        int idx = i * 256 + tid;
        int c4 = idx & 31, k = idx >> 5;
        float4 wv = *(const float4*)(fc_w + k * C_ + c4 * 4);
        _Float16 h0 = (_Float16)wv.x, h1 = (_Float16)wv.y,
                 h2 = (_Float16)wv.z, h3 = (_Float16)wv.w;
        f16x4 hi = {h0, h1, h2, h3};
        f16x4 lo = {(_Float16)(wv.x - (float)h0), (_Float16)(wv.y - (float)h1),
                    (_Float16)(wv.z - (float)h2), (_Float16)(wv.w - (float)h3)};
        int e = k * 128 + ((c4 * 4) ^ ((k & 7) << 3));
        *(f16x4*)&Wh[e] = hi;
        *(f16x4*)&Wl[e] = lo;
    }
    {
        float* rp = &rns[0][0];
        rp[tid] = 0.f;
        rp[256 + tid] = 0.f;
    }

    float bias[4];
#pragma unroll
    for (int nt = 0; nt < 4; ++nt) bias[nt] = fc_b[nt * 16 + lr];
    float a_acc[4] = {0.f, 0.f, 0.f, 0.f};
    f32x4 vacc[8];
#pragma unroll
    for (int nt = 0; nt < 8; ++nt) vacc[nt] = (f32x4){0.f, 0.f, 0.f, 0.f};

    const float* xb = x + (size_t)n * C_ * S_;
    const int s4 = tid & 15;
    int cqv[2];
#pragma unroll
    for (int i = 0; i < 2; ++i) cqv[i] = i * 16 + (tid >> 4);

    // prefetch tile 0 into registers (2 c-quads x 4 rows x float4-of-s)
    float4 pre[2][4];
#pragma unroll
    for (int i = 0; i < 2; ++i)
#pragma unroll
        for (int cc = 0; cc < 4; ++cc)
            pre[i][cc] = *(const float4*)(xb + (size_t)(cqv[i] * 4 + cc) * S_ +
                                          chunk * 512 + s4 * 4);

#pragma unroll 1
    for (int t = 0; t < 8; ++t) {
        __syncthreads();   // prev tile's LDS fully consumed (W/rns ready @t=0)
        // ---- stage from regs: xT (4x4 transpose) + xC + norm partials ----
        float part[4] = {0.f, 0.f, 0.f, 0.f};
#pragma unroll
        for (int i = 0; i < 2; ++i) {
            int cq = cqv[i];
#pragma unroll
            for (int j = 0; j < 4; ++j) {
                float v0 = (&pre[i][0].x)[j], v1 = (&pre[i][1].x)[j],
                      v2 = (&pre[i][2].x)[j], v3 = (&pre[i][3].x)[j];
                part[j] += v0 * v0 + v1 * v1 + v2 * v2 + v3 * v3;
                f16x4 p = {(_Float16)v0, (_Float16)v1, (_Float16)v2, (_Float16)v3};
                int s = s4 * 4 + j;
                *(f16x4*)&xT[s * 128 + ((cq * 4) ^ SWZ_S(s))] = p;
            }
#pragma unroll
            for (int cc = 0; cc < 4; ++cc) {
                int c = cq * 4 + cc;
                f16x4 q = {(_Float16)pre[i][cc].x, (_Float16)pre[i][cc].y,
                           (_Float16)pre[i][cc].z, (_Float16)pre[i][cc].w};
                *(f16x4*)&xC[c * 64 + ((s4 * 4) ^ ((c & 7) << 3))] = q;
            }
        }
        // in-wave reduce over the wave's 32 c, then 1 atomic per (s-col, wave)
#pragma unroll
        for (int j = 0; j < 4; ++j) {
            part[j] += __shfl_xor(part[j], 16);
            part[j] += __shfl_xor(part[j], 32);
        }
        if (g == 0) {
#pragma unroll
            for (int j = 0; j < 4; ++j)
                atomicAdd(&rns[t][lr * 4 + j], part[j]);
        }
        // issue next tile's loads (regs only) to overlap with GEMM phases
        if (t < 7) {
#pragma unroll
            for (int i = 0; i < 2; ++i)
#pragma unroll
                for (int cc = 0; cc < 4; ++cc)
                    pre[i][cc] = *(const float4*)(xb + (size_t)(cqv[i] * 4 + cc) * S_ +
                                                  chunk * 512 + (t + 1) * 64 + s4 * 4);
        }
        __syncthreads();

        // ---- logits GEMM: D[s][k], wave w owns s-rows [16w,16w+16) ----
        f32x4 acc[4];
#pragma unroll
        for (int nt = 0; nt < 4; ++nt) acc[nt] = (f32x4){0.f, 0.f, 0.f, 0.f};
#pragma unroll
        for (int kt = 0; kt < 4; ++kt) {
            const int co = kt * 32 + g * 8;
            const int sa = w * 16 + lr;
            f16x8 af = *(const f16x8*)&xT[sa * 128 + (co ^ SWZ_S(sa))];
            f16x8 whf[4], wlf[4];
#pragma unroll
            for (int nt = 0; nt < 4; ++nt) {
                int e = (nt * 16 + lr) * 128 + (co ^ fsw);
                whf[nt] = *(const f16x8*)&Wh[e];
                wlf[nt] = *(const f16x8*)&Wl[e];
            }
#pragma unroll
            for (int nt = 0; nt < 4; ++nt) {
                acc[nt] = __builtin_amdgcn_mfma_f32_16x16x32_f16(af, whf[nt], acc[nt], 0, 0, 0);
                acc[nt] = __builtin_amdgcn_mfma_f32_16x16x32_f16(af, wlf[nt], acc[nt], 0, 0, 0);
            }
        }

        // ---- softmax over k (4 nt regs x 16 lr lanes), soft' -> sst ----
        {
            float rnl[4], ai[4];
#pragma unroll
            for (int r = 0; r < 4; ++r) {
                float ss = rns[t][w * 16 + g * 4 + r];
                rnl[r] = 1.0f / fmaxf(sqrtf(ss), 1e-12f);
            }
#pragma unroll
            for (int nt = 0; nt < 4; ++nt)
#pragma unroll
                for (int r = 0; r < 4; ++r)
                    acc[nt][r] = __expf(acc[nt][r] * rnl[r] + bias[nt]);
#pragma unroll
            for (int r = 0; r < 4; ++r) {
                float sum = (acc[0][r] + acc[1][r]) + (acc[2][r] + acc[3][r]);
                sum += __shfl_xor(sum, 1);
                sum += __shfl_xor(sum, 2);
                sum += __shfl_xor(sum, 4);
                sum += __shfl_xor(sum, 8);
                float bi = 1.0f / sum;
                ai[r] = bi * rnl[r];
#pragma unroll
                for (int nt = 0; nt < 4; ++nt) a_acc[nt] += acc[nt][r] * bi;
            }
#pragma unroll
            for (int nt = 0; nt < 4; ++nt) {
                int k = nt * 16 + lr;
                int sloc = w * 16 + g * 4;
                f16x4 p = {(_Float16)(acc[nt][0] * ai[0]), (_Float16)(acc[nt][1] * ai[1]),
                           (_Float16)(acc[nt][2] * ai[2]), (_Float16)(acc[nt][3] * ai[3])};
                *(f16x4*)&sst[k * 64 + (sloc ^ ((k & 7) << 3))] = p;
            }
        }
        __syncthreads();

        // ---- vlad GEMM: D[k][c], wave w owns k-tile w; accumulate vacc ----
#pragma unroll
        for (int kt = 0; kt < 2; ++kt) {
            const int so = kt * 32 + g * 8;
            f16x8 pa = *(const f16x8*)&sst[(w * 16 + lr) * 64 + (so ^ fsw)];
#pragma unroll
            for (int nt = 0; nt < 8; ++nt) {
                f16x8 xv = *(const f16x8*)&xC[(nt * 16 + lr) * 64 + (so ^ fsw)];
                vacc[nt] = __builtin_amdgcn_mfma_f32_16x16x32_f16(pa, xv, vacc[nt], 0, 0, 0);
            }
        }
    }

    // ---- flush vlad partials + a_sum ----
    float* vp = vlad_acc + ((size_t)n * K_ + w * 16) * C_;
#pragma unroll
    for (int nt = 0; nt < 8; ++nt)
#pragma unroll
        for (int r = 0; r < 4; ++r)
            atomicAdd(vp + (g * 4 + r) * C_ + nt * 16 + lr, vacc[nt][r]);
#pragma unroll
    for (int nt = 0; nt < 4; ++nt) {
        a_acc[nt] += __shfl_xor(a_acc[nt], 16);
        a_acc[nt] += __shfl_xor(a_acc[nt], 32);
    }
    if (lane < 16) {
#pragma unroll
        for (int nt = 0; nt < 4; ++nt)
            atomicAdd(a_sum + n * K_ + nt * 16 + lr, a_acc[nt]);
    }
}

// ---------------------------------------------------------------------------
// Finalize: vlad -= a_sum*centroids; intra-norm over C; global norm.
// ---------------------------------------------------------------------------
__global__ __launch_bounds__(256) void finalize_kernel(
    const float* __restrict__ vlad_acc, const float* __restrict__ a_sum,
    const float* __restrict__ centroids, float* __restrict__ out)
{
    __shared__ float red[4];
    const int n = blockIdx.x;
    const int t = threadIdx.x;
    const int k = t >> 2, q = t & 3;
    const float av = a_sum[n * K_ + k];
    const float* vp = vlad_acc + ((size_t)n * K_ + k) * C_;
    const float* cp = centroids + k * C_;

    float v[32];
    float ssq = 0.f;
#pragma unroll
    for (int j = 0; j < 32; ++j) {
        int c = q + 4 * j;
        float val = vp[c] - av * cp[c];
        v[j] = val;
        ssq += val * val;
    }
    ssq += __shfl_xor(ssq, 1);
    ssq += __shfl_xor(ssq, 2);
    const float inv1 = 1.0f / fmaxf(sqrtf(ssq), 1e-12f);

    float gp = (q == 0) ? ssq * inv1 * inv1 : 0.f;
#pragma unroll
    for (int off = 1; off < 64; off <<= 1) gp += __shfl_xor(gp, off);
    if ((t & 63) == 0) red[t >> 6] = gp;
    __syncthreads();
    const float G = red[0] + red[1] + red[2] + red[3];
    const float ginv = 1.0f / fmaxf(sqrtf(G), 1e-12f);

    float* op = out + (size_t)n * (K_ * C_) + k * C_;
#pragma unroll
    for (int j = 0; j < 32; ++j) op[q + 4 * j] = v[j] * inv1 * ginv;
}

extern "C" void kernel_launch(void* const* d_in, const int* in_sizes, int n_in,
                              void* d_out, int out_size, void* d_ws, size_t ws_size,
                              hipStream_t stream) {
    const float* x     = (const float*)d_in[0];
    const float* fc_w  = (const float*)d_in[1];
    const float* fc_b  = (const float*)d_in[2];
    const float* cent  = (const float*)d_in[3];
    float* out = (float*)d_out;

    char* ws = (char*)d_ws;
    float* a_sum = (float*)ws;                 // 4 KB (N*K = 1024 floats)
    float* vlad  = (float*)(ws + 4096);        // 512 KB

    hipMemsetAsync(ws, 0, 4096 + (size_t)N_ * K_ * C_ * sizeof(float), stream);

    fused_kernel<<<N_ * 32, 256, 0, stream>>>(x, fc_w, fc_b, vlad, a_sum);
    finalize_kernel<<<N_, 256, 0, stream>>>(vlad, a_sum, cent, out);
}

// Round 6
// 51.950 us; speedup vs baseline: 5.8116x; 1.1624x over previous
//
#include <hip/hip_runtime.h>
#include <hip/hip_fp16.h>

#define N_ 16
#define C_ 128
#define S_ 16384
#define K_ 64

typedef __attribute__((ext_vector_type(4))) float f32x4;
typedef __attribute__((ext_vector_type(8))) _Float16 f16x8;
typedef __attribute__((ext_vector_type(4))) _Float16 f16x4;

// xT row-swizzle: varies with staging rows s=4*s4+j AND frag rows s=16m+lr.
#define SWZ_S(s) ((((s) ^ ((s) >> 3)) & 7) << 3)

// ---------------------------------------------------------------------------
// Fused v3: 64-s tiles, 8 per block. W fragments live in REGISTERS (single
// f16, loaded per-lane from global once). xC double-buffered so vlad(t-1)
// interleaves with stage(t) in the same segment; 2 barriers/tile.
// No global atomics: per-block partial slabs, reduced by reduce_kernel.
// LDS = 16 (xT) + 32 (xC[2]) + 8 (sst) + 2 (rns) = 58 KB -> 2 blocks/CU.
// ---------------------------------------------------------------------------
__global__ __launch_bounds__(256, 2) void fused_kernel(
    const float* __restrict__ x, const float* __restrict__ fc_w,
    const float* __restrict__ fc_b, float* __restrict__ vlad_part,
    float* __restrict__ a_part)
{
    __shared__ _Float16 xT[64 * 128];     // 16 KB [s][c]
    __shared__ _Float16 xC[2][128 * 64];  // 32 KB [c][s] double-buffered
    __shared__ _Float16 sst[64 * 64];     //  8 KB [k][s]
    __shared__ float rns[8][64];          //  2 KB per-tile col ssq

    const int tid = threadIdx.x;
    const int n = blockIdx.x >> 5;
    const int chunk = blockIdx.x & 31;
    const int lane = tid & 63, w = tid >> 6;
    const int lr = lane & 15, g = lane >> 4;
    const int fsw = (lr & 7) << 3;        // swizzle for rows of form m*16+lr

    // ---- W B-fragments in registers (tile-invariant): row k=nt*16+lr,
    //      c-slice kt*32+g*8 .. +8  (same mapping as the old LDS frag reads)
    f16x8 wfrag[4][4];
#pragma unroll
    for (int nt = 0; nt < 4; ++nt)
#pragma unroll
        for (int kt = 0; kt < 4; ++kt) {
            const float* wp = fc_w + (nt * 16 + lr) * C_ + kt * 32 + g * 8;
            float4 wa = *(const float4*)wp;
            float4 wb = *(const float4*)(wp + 4);
            f16x8 f;
            f[0] = (_Float16)wa.x; f[1] = (_Float16)wa.y;
            f[2] = (_Float16)wa.z; f[3] = (_Float16)wa.w;
            f[4] = (_Float16)wb.x; f[5] = (_Float16)wb.y;
            f[6] = (_Float16)wb.z; f[7] = (_Float16)wb.w;
            wfrag[nt][kt] = f;
        }

    {   // zero rns (8 tiles x 64 s)
        float* rp = &rns[0][0];
        rp[tid] = 0.f;
        rp[256 + tid] = 0.f;
    }

    float bias[4];
#pragma unroll
    for (int nt = 0; nt < 4; ++nt) bias[nt] = fc_b[nt * 16 + lr];
    float a_acc[4] = {0.f, 0.f, 0.f, 0.f};
    f32x4 vacc[8];
#pragma unroll
    for (int nt = 0; nt < 8; ++nt) vacc[nt] = (f32x4){0.f, 0.f, 0.f, 0.f};

    const float* xb = x + (size_t)n * C_ * S_;
    const int s4 = tid & 15;
    int cqv[2];
#pragma unroll
    for (int i = 0; i < 2; ++i) cqv[i] = i * 16 + (tid >> 4);

    // prefetch tile 0 (2 c-quads x 4 c-rows x float4-of-s)
    float4 pre[2][4];
#pragma unroll
    for (int i = 0; i < 2; ++i)
#pragma unroll
        for (int cc = 0; cc < 4; ++cc)
            pre[i][cc] = *(const float4*)(xb + (size_t)(cqv[i] * 4 + cc) * S_ +
                                          chunk * 512 + s4 * 4);

#pragma unroll 1
    for (int t = 0; t < 8; ++t) {
        const int b = t & 1;
        __syncthreads();  // sst(t-1) complete; xC[b] free; rns init @t=0

        // ---- stage tile t: xT + xC[b] + norm partials ----
        float part[4] = {0.f, 0.f, 0.f, 0.f};
#pragma unroll
        for (int i = 0; i < 2; ++i) {
            int cq = cqv[i];
#pragma unroll
            for (int j = 0; j < 4; ++j) {
                float v0 = (&pre[i][0].x)[j], v1 = (&pre[i][1].x)[j],
                      v2 = (&pre[i][2].x)[j], v3 = (&pre[i][3].x)[j];
                part[j] += v0 * v0 + v1 * v1 + v2 * v2 + v3 * v3;
                f16x4 p = {(_Float16)v0, (_Float16)v1, (_Float16)v2, (_Float16)v3};
                int s = s4 * 4 + j;
                *(f16x4*)&xT[s * 128 + ((cq * 4) ^ SWZ_S(s))] = p;
            }
#pragma unroll
            for (int cc = 0; cc < 4; ++cc) {
                int c = cq * 4 + cc;
                f16x4 q = {(_Float16)pre[i][cc].x, (_Float16)pre[i][cc].y,
                           (_Float16)pre[i][cc].z, (_Float16)pre[i][cc].w};
                *(f16x4*)&xC[b][c * 64 + ((s4 * 4) ^ ((c & 7) << 3))] = q;
            }
        }
#pragma unroll
        for (int j = 0; j < 4; ++j) {
            part[j] += __shfl_xor(part[j], 16);
            part[j] += __shfl_xor(part[j], 32);
        }
        if (g == 0) {
#pragma unroll
            for (int j = 0; j < 4; ++j)
                atomicAdd(&rns[t][lr * 4 + j], part[j]);
        }
        // prefetch tile t+1 (global->regs, hides under vlad+logits)
        if (t < 7) {
#pragma unroll
            for (int i = 0; i < 2; ++i)
#pragma unroll
                for (int cc = 0; cc < 4; ++cc)
                    pre[i][cc] = *(const float4*)(xb + (size_t)(cqv[i] * 4 + cc) * S_ +
                                                  chunk * 512 + (t + 1) * 64 + s4 * 4);
        }

        // ---- vlad(t-1) interleaved with stage: reads sst + xC[b^1] ----
        if (t > 0) {
            const _Float16* xcp = xC[b ^ 1];
#pragma unroll
            for (int kt = 0; kt < 2; ++kt) {
                const int so = kt * 32 + g * 8;
                f16x8 pa = *(const f16x8*)&sst[(w * 16 + lr) * 64 + (so ^ fsw)];
#pragma unroll
                for (int nt = 0; nt < 8; ++nt) {
                    f16x8 xv = *(const f16x8*)&xcp[(nt * 16 + lr) * 64 + (so ^ fsw)];
                    vacc[nt] = __builtin_amdgcn_mfma_f32_16x16x32_f16(pa, xv, vacc[nt], 0, 0, 0);
                }
            }
        }
        __syncthreads();  // xT/xC[b]/rns visible; sst free (vlad(t-1) done)

        // ---- logits GEMM: D[s][k], wave w owns s-rows [16w,16w+16) ----
        f32x4 acc[4];
#pragma unroll
        for (int nt = 0; nt < 4; ++nt) acc[nt] = (f32x4){0.f, 0.f, 0.f, 0.f};
#pragma unroll
        for (int kt = 0; kt < 4; ++kt) {
            const int co = kt * 32 + g * 8;
            const int sa = w * 16 + lr;
            f16x8 af = *(const f16x8*)&xT[sa * 128 + (co ^ SWZ_S(sa))];
#pragma unroll
            for (int nt = 0; nt < 4; ++nt)
                acc[nt] = __builtin_amdgcn_mfma_f32_16x16x32_f16(af, wfrag[nt][kt], acc[nt], 0, 0, 0);
        }

        // ---- softmax over k (4 nt regs x 16 lr lanes), soft' -> sst ----
        {
            float rnl[4], ai[4];
#pragma unroll
            for (int r = 0; r < 4; ++r) {
                float ss = rns[t][w * 16 + g * 4 + r];
                rnl[r] = 1.0f / fmaxf(sqrtf(ss), 1e-12f);
            }
#pragma unroll
            for (int nt = 0; nt < 4; ++nt)
#pragma unroll
                for (int r = 0; r < 4; ++r)
                    acc[nt][r] = __expf(acc[nt][r] * rnl[r] + bias[nt]);
#pragma unroll
            for (int r = 0; r < 4; ++r) {
                float sum = (acc[0][r] + acc[1][r]) + (acc[2][r] + acc[3][r]);
                sum += __shfl_xor(sum, 1);
                sum += __shfl_xor(sum, 2);
                sum += __shfl_xor(sum, 4);
                sum += __shfl_xor(sum, 8);
                float bi = 1.0f / sum;
                ai[r] = bi * rnl[r];
#pragma unroll
                for (int nt = 0; nt < 4; ++nt) a_acc[nt] += acc[nt][r] * bi;
            }
#pragma unroll
            for (int nt = 0; nt < 4; ++nt) {
                int k = nt * 16 + lr;
                int sloc = w * 16 + g * 4;
                f16x4 p = {(_Float16)(acc[nt][0] * ai[0]), (_Float16)(acc[nt][1] * ai[1]),
                           (_Float16)(acc[nt][2] * ai[2]), (_Float16)(acc[nt][3] * ai[3])};
                *(f16x4*)&sst[k * 64 + (sloc ^ ((k & 7) << 3))] = p;
            }
        }
    }

    // ---- epilogue: vlad(7), then flush partials (plain stores) ----
    __syncthreads();
    {
        const _Float16* xcp = xC[1];   // tile 7 parity
#pragma unroll
        for (int kt = 0; kt < 2; ++kt) {
            const int so = kt * 32 + g * 8;
            f16x8 pa = *(const f16x8*)&sst[(w * 16 + lr) * 64 + (so ^ fsw)];
#pragma unroll
            for (int nt = 0; nt < 8; ++nt) {
                f16x8 xv = *(const f16x8*)&xcp[(nt * 16 + lr) * 64 + (so ^ fsw)];
                vacc[nt] = __builtin_amdgcn_mfma_f32_16x16x32_f16(pa, xv, vacc[nt], 0, 0, 0);
            }
        }
    }
    float* vp = vlad_part + (size_t)blockIdx.x * (K_ * C_) + (w * 16) * C_;
#pragma unroll
    for (int nt = 0; nt < 8; ++nt)
#pragma unroll
        for (int r = 0; r < 4; ++r)
            vp[(g * 4 + r) * C_ + nt * 16 + lr] = vacc[nt][r];
#pragma unroll
    for (int nt = 0; nt < 4; ++nt) {
        a_acc[nt] += __shfl_xor(a_acc[nt], 16);
        a_acc[nt] += __shfl_xor(a_acc[nt], 32);
    }
    if (lane < 16) {
#pragma unroll
        for (int nt = 0; nt < 4; ++nt)
            a_part[blockIdx.x * 256 + w * 64 + nt * 16 + lr] = a_acc[nt];
    }
}

// ---------------------------------------------------------------------------
// Reduce chunk partials: vlad_sum[n][k][c] = sum_ch vlad_part[n*32+ch][k][c]
// ---------------------------------------------------------------------------
__global__ __launch_bounds__(256) void reduce_kernel(
    const float* __restrict__ vlad_part, float* __restrict__ vlad_sum)
{
    const int n = blockIdx.x >> 5, g8 = blockIdx.x & 31;
    const int e = g8 * 256 + threadIdx.x;        // (k*128+c)
    const float* p = vlad_part + (size_t)(n * 32) * (K_ * C_) + e;
    float acc = 0.f;
#pragma unroll
    for (int ch = 0; ch < 32; ++ch) acc += p[(size_t)ch * (K_ * C_)];
    vlad_sum[n * (K_ * C_) + e] = acc;
}

// ---------------------------------------------------------------------------
// Finalize: a_sum reduce; vlad -= a_sum*centroids; intra-norm; global norm.
// Grid 16 x 1024. Thread t: k = t>>4, q = t&15, c = q + 16j (j<8).
// ---------------------------------------------------------------------------
__global__ __launch_bounds__(1024) void finalize_kernel(
    const float* __restrict__ vlad_sum, const float* __restrict__ a_part,
    const float* __restrict__ centroids, float* __restrict__ out)
{
    __shared__ float red[16];
    const int n = blockIdx.x;
    const int t = threadIdx.x;
    const int k = t >> 4, q = t & 15;

    // a_sum[k]: sum over 32 chunks x 4 waves of a_part[(n*32+ch)*256 + w*64 + k]
    float av = 0.f;
#pragma unroll
    for (int cc = 0; cc < 2; ++cc) {
        int ch = q * 2 + cc;
        const float* ap = a_part + (size_t)(n * 32 + ch) * 256 + k;
#pragma unroll
        for (int ww = 0; ww < 4; ++ww) av += ap[ww * 64];
    }
    av += __shfl_xor(av, 1);
    av += __shfl_xor(av, 2);
    av += __shfl_xor(av, 4);
    av += __shfl_xor(av, 8);

    const float* vp = vlad_sum + (size_t)n * (K_ * C_) + k * C_;
    const float* cp = centroids + k * C_;
    float v[8];
    float ssq = 0.f;
#pragma unroll
    for (int j = 0; j < 8; ++j) {
        int c = q + 16 * j;
        float val = vp[c] - av * cp[c];
        v[j] = val;
        ssq += val * val;
    }
    ssq += __shfl_xor(ssq, 1);
    ssq += __shfl_xor(ssq, 2);
    ssq += __shfl_xor(ssq, 4);
    ssq += __shfl_xor(ssq, 8);
    const float inv1 = 1.0f / fmaxf(sqrtf(ssq), 1e-12f);

    float gp = (q == 0) ? ssq * inv1 * inv1 : 0.f;
#pragma unroll
    for (int off = 1; off < 64; off <<= 1) gp += __shfl_xor(gp, off);
    if ((t & 63) == 0) red[t >> 6] = gp;
    __syncthreads();
    float G = 0.f;
#pragma unroll
    for (int i = 0; i < 16; ++i) G += red[i];
    const float ginv = 1.0f / fmaxf(sqrtf(G), 1e-12f);

    float* op = out + (size_t)n * (K_ * C_) + k * C_;
#pragma unroll
    for (int j = 0; j < 8; ++j) op[q + 16 * j] = v[j] * inv1 * ginv;
}

extern "C" void kernel_launch(void* const* d_in, const int* in_sizes, int n_in,
                              void* d_out, int out_size, void* d_ws, size_t ws_size,
                              hipStream_t stream) {
    const float* x     = (const float*)d_in[0];
    const float* fc_w  = (const float*)d_in[1];
    const float* fc_b  = (const float*)d_in[2];
    const float* cent  = (const float*)d_in[3];
    float* out = (float*)d_out;

    char* ws = (char*)d_ws;
    float* vlad_part = (float*)ws;                                   // 16 MB
    float* a_part    = (float*)(ws + (size_t)512 * K_ * C_ * 4);     // 512 KB
    float* vlad_sum  = (float*)(ws + (size_t)512 * K_ * C_ * 4 + 512 * 1024);

    fused_kernel<<<N_ * 32, 256, 0, stream>>>(x, fc_w, fc_b, vlad_part, a_part);
    reduce_kernel<<<N_ * 32, 256, 0, stream>>>(vlad_part, vlad_sum);
    finalize_kernel<<<N_, 1024, 0, stream>>>(vlad_sum, a_part, cent, out);
}